// Round 1
// baseline (5822.061 us; speedup 1.0000x reference)
//
#include <hip/hip_runtime.h>
#include <cstdint>
#include <cstddef>

#define N_NODES 100000
#define N_EDGES 1600000
#define HID 128

// ---------------------------------------------------------------- deg / dinv
__global__ __launch_bounds__(256) void k_count(const int* __restrict__ col,
                                               int* __restrict__ deg) {
    int e = blockIdx.x * 256 + threadIdx.x;
    if (e < N_EDGES) atomicAdd(&deg[col[e]], 1);
}

__global__ __launch_bounds__(256) void k_dinv(const int* __restrict__ deg,
                                              float* __restrict__ dinv) {
    int i = blockIdx.x * 256 + threadIdx.x;
    if (i < N_NODES) dinv[i] = rsqrtf((float)deg[i] + 1.0f);  // +1 self-loop
}

// ---------------------------------------------------------------- fp32 GEMM
// C[M,128] = A[M,K] @ W[K,128]; M = N_NODES (divisible by 32).
// Block: 256 threads, 32-row tile, each thread 4x4 micro-tile.
// A tile staged in LDS (contiguous row chunk -> straight float4 copy).
// W (<=128 KB) is L2-resident; read directly per-k (one 512B line per wave).
template <int K>
__global__ __launch_bounds__(256) void k_gemm(const float* __restrict__ A,
                                              const float* __restrict__ W,
                                              float* __restrict__ C) {
    __shared__ float As[32 * K];
    const int tid = threadIdx.x;
    const size_t m0 = (size_t)blockIdx.x * 32;

    const float4* Ag = reinterpret_cast<const float4*>(A + m0 * K);
    float4* As4 = reinterpret_cast<float4*>(As);
#pragma unroll
    for (int i = tid; i < 32 * K / 4; i += 256) As4[i] = Ag[i];
    __syncthreads();

    const int c0 = (tid & 31) * 4;   // output col base
    const int r0 = (tid >> 5) * 4;   // output row base (within tile)
    float acc[4][4] = {};

#pragma unroll 4
    for (int k = 0; k < K; ++k) {
        const float4 bv = *reinterpret_cast<const float4*>(W + k * HID + c0);
#pragma unroll
        for (int i = 0; i < 4; ++i) {
            const float a = As[(r0 + i) * K + k];  // 2-way bcast, conflict-free
            acc[i][0] += a * bv.x;
            acc[i][1] += a * bv.y;
            acc[i][2] += a * bv.z;
            acc[i][3] += a * bv.w;
        }
    }
#pragma unroll
    for (int i = 0; i < 4; ++i) {
        *reinterpret_cast<float4*>(C + (m0 + r0 + i) * HID + c0) =
            make_float4(acc[i][0], acc[i][1], acc[i][2], acc[i][3]);
    }
}

// ---------------------------------------------------------------- scatter-add
// out[col[e]] += dinv[row[e]]*dinv[col[e]] * xw[row[e]]   (128 dims/edge)
// 32 threads per edge, float4 per thread: 512B coalesced gather per edge.
__global__ __launch_bounds__(256) void k_scatter(const float* __restrict__ xw,
                                                 const int* __restrict__ row,
                                                 const int* __restrict__ col,
                                                 const float* __restrict__ dinv,
                                                 float* __restrict__ out) {
    const int idx = blockIdx.x * 256 + threadIdx.x;  // E*32 = 51.2M items
    const int e = idx >> 5;
    if (e >= N_EDGES) return;
    const int ch = (idx & 31) * 4;
    const int r = row[e];
    const int c = col[e];
    const float nrm = dinv[r] * dinv[c];
    const float4 v = *reinterpret_cast<const float4*>(xw + (size_t)r * HID + ch);
    float* o = out + (size_t)c * HID + ch;
    atomicAdd(o + 0, nrm * v.x);
    atomicAdd(o + 1, nrm * v.y);
    atomicAdd(o + 2, nrm * v.z);
    atomicAdd(o + 3, nrm * v.w);
}

// ---------------------------------------------------------------- epilogue
// out = tanh(agg + dinv[i]^2 * xw[i,:] + b)   (self-loop folded in here)
__global__ __launch_bounds__(256) void k_bias_act(const float* __restrict__ agg,
                                                  const float* __restrict__ xw,
                                                  const float* __restrict__ dinv,
                                                  const float* __restrict__ b,
                                                  float* __restrict__ out) {
    const int idx = blockIdx.x * 256 + threadIdx.x;  // N*32 items
    if (idx >= N_NODES * 32) return;
    const int i = idx >> 5;
    const int ch = (idx & 31) * 4;
    const float s = dinv[i] * dinv[i];
    const float4 av = *reinterpret_cast<const float4*>(agg + (size_t)i * HID + ch);
    const float4 xv = *reinterpret_cast<const float4*>(xw + (size_t)i * HID + ch);
    const float4 bv = *reinterpret_cast<const float4*>(b + ch);
    float4 o;
    o.x = tanhf(av.x + s * xv.x + bv.x);
    o.y = tanhf(av.y + s * xv.y + bv.y);
    o.z = tanhf(av.z + s * xv.z + bv.z);
    o.w = tanhf(av.w + s * xv.w + bv.w);
    *reinterpret_cast<float4*>(out + (size_t)i * HID + ch) = o;
}

// ---------------------------------------------------------------- launch
extern "C" void kernel_launch(void* const* d_in, const int* in_sizes, int n_in,
                              void* d_out, int out_size, void* d_ws, size_t ws_size,
                              hipStream_t stream) {
    const float* x  = (const float*)d_in[0];
    const int*   ei = (const int*)d_in[1];      // [2, E] flat
    const int*   row = ei;                      // edge_index[0]
    const int*   col = ei + N_EDGES;            // edge_index[1]
    const float* W1 = (const float*)d_in[2];
    const float* b1 = (const float*)d_in[3];
    const float* W2 = (const float*)d_in[4];
    const float* b2 = (const float*)d_in[5];
    float* out = (float*)d_out;

    // workspace layout (fp32): xw | agg | dinv | deg(int)  ~= 103 MB
    float* xw   = (float*)d_ws;
    float* agg  = xw + (size_t)N_NODES * HID;
    float* dinv = agg + (size_t)N_NODES * HID;
    int*   deg  = (int*)(dinv + N_NODES);

    // graph norm (shared by both layers)
    hipMemsetAsync(deg, 0, N_NODES * sizeof(int), stream);
    k_count<<<(N_EDGES + 255) / 256, 256, 0, stream>>>(col, deg);
    k_dinv<<<(N_NODES + 255) / 256, 256, 0, stream>>>(deg, dinv);

    // ---- layer 1: h1 = tanh(scatter(x@W1) + dinv^2*(x@W1) + b1), h1 -> agg (in place)
    k_gemm<256><<<N_NODES / 32, 256, 0, stream>>>(x, W1, xw);
    hipMemsetAsync(agg, 0, (size_t)N_NODES * HID * sizeof(float), stream);
    k_scatter<<<(N_EDGES * 32) / 256, 256, 0, stream>>>(xw, row, col, dinv, agg);
    k_bias_act<<<(N_NODES * 32 + 255) / 256, 256, 0, stream>>>(agg, xw, dinv, b1, agg);

    // ---- layer 2: out = tanh(scatter(h1@W2) + dinv^2*(h1@W2) + b2)
    k_gemm<128><<<N_NODES / 32, 256, 0, stream>>>(agg, W2, xw);
    hipMemsetAsync(agg, 0, (size_t)N_NODES * HID * sizeof(float), stream);
    k_scatter<<<(N_EDGES * 32) / 256, 256, 0, stream>>>(xw, row, col, dinv, agg);
    k_bias_act<<<(N_NODES * 32 + 255) / 256, 256, 0, stream>>>(agg, xw, dinv, b2, out);
}

// Round 4
// 773.101 us; speedup vs baseline: 7.5308x; 7.5308x over previous
//
#include <hip/hip_runtime.h>
#include <cstdint>
#include <cstddef>

#define N_NODES 100000
#define N_EDGES 1600000
#define HID 128
#define SCAN_BLOCKS ((N_NODES + 255) / 256)   // 391

// ---------------------------------------------------------------- deg histogram
__global__ __launch_bounds__(256) void k_count(const int* __restrict__ col,
                                               int* __restrict__ deg) {
    int e = blockIdx.x * 256 + threadIdx.x;
    if (e < N_EDGES) atomicAdd(&deg[col[e]], 1);
}

__global__ __launch_bounds__(256) void k_dinv(const int* __restrict__ deg,
                                              float* __restrict__ dinv) {
    int i = blockIdx.x * 256 + threadIdx.x;
    if (i < N_NODES) dinv[i] = rsqrtf((float)deg[i] + 1.0f);  // +1 self-loop
}

// ---------------------------------------------------------------- exclusive scan (3 kernels)
__global__ __launch_bounds__(256) void k_scan1(const int* __restrict__ deg,
                                               int* __restrict__ cursor,
                                               int* __restrict__ bsum) {
    __shared__ int s[256];
    const int t = threadIdx.x;
    const int i = blockIdx.x * 256 + t;
    int v = (i < N_NODES) ? deg[i] : 0;
    s[t] = v;
    __syncthreads();
#pragma unroll
    for (int d = 1; d < 256; d <<= 1) {
        int a = (t >= d) ? s[t - d] : 0;
        __syncthreads();
        s[t] += a;
        __syncthreads();
    }
    if (i < N_NODES) cursor[i] = s[t] - v;           // exclusive within block
    if (t == 255) bsum[blockIdx.x] = s[t];           // block total
}

__global__ __launch_bounds__(512) void k_scan2(int* __restrict__ bsum, int n) {
    __shared__ int s[512];
    const int t = threadIdx.x;
    int v = (t < n) ? bsum[t] : 0;
    s[t] = v;
    __syncthreads();
#pragma unroll
    for (int d = 1; d < 512; d <<= 1) {
        int a = (t >= d) ? s[t - d] : 0;
        __syncthreads();
        s[t] += a;
        __syncthreads();
    }
    if (t < n) bsum[t] = s[t] - v;                   // exclusive block offsets
}

__global__ __launch_bounds__(256) void k_scan3(int* __restrict__ cursor,
                                               const int* __restrict__ bsum) {
    const int i = blockIdx.x * 256 + threadIdx.x;
    if (i < N_NODES) cursor[i] += bsum[blockIdx.x];
}

// ---------------------------------------------------------------- CSR placement
// After this kernel cursor[c] = end of segment c (start is cursor[c-1], or 0).
__global__ __launch_bounds__(256) void k_place(const int* __restrict__ row,
                                               const int* __restrict__ col,
                                               const float* __restrict__ dinv,
                                               int* __restrict__ cursor,
                                               int* __restrict__ srow,
                                               float* __restrict__ sdnv) {
    const int e = blockIdx.x * 256 + threadIdx.x;
    if (e >= N_EDGES) return;
    const int r = row[e];
    const int c = col[e];
    const int p = atomicAdd(&cursor[c], 1);
    srow[p] = r;
    sdnv[p] = dinv[r];
}

// ---------------------------------------------------------------- fp32 GEMM
// C[M,128] = A[M,K] @ W[K,128]; 32-row tile, 256 threads, 4x4 micro-tile.
template <int K>
__global__ __launch_bounds__(256) void k_gemm(const float* __restrict__ A,
                                              const float* __restrict__ W,
                                              float* __restrict__ C) {
    __shared__ float As[32 * K];
    const int tid = threadIdx.x;
    const size_t m0 = (size_t)blockIdx.x * 32;

    const float4* Ag = reinterpret_cast<const float4*>(A + m0 * K);
    float4* As4 = reinterpret_cast<float4*>(As);
#pragma unroll
    for (int i = tid; i < 32 * K / 4; i += 256) As4[i] = Ag[i];
    __syncthreads();

    const int c0 = (tid & 31) * 4;
    const int r0 = (tid >> 5) * 4;
    float acc[4][4] = {};

#pragma unroll 4
    for (int k = 0; k < K; ++k) {
        const float4 bv = *reinterpret_cast<const float4*>(W + k * HID + c0);
#pragma unroll
        for (int i = 0; i < 4; ++i) {
            const float a = As[(r0 + i) * K + k];
            acc[i][0] += a * bv.x;
            acc[i][1] += a * bv.y;
            acc[i][2] += a * bv.z;
            acc[i][3] += a * bv.w;
        }
    }
#pragma unroll
    for (int i = 0; i < 4; ++i) {
        *reinterpret_cast<float4*>(C + (m0 + r0 + i) * HID + c0) =
            make_float4(acc[i][0], acc[i][1], acc[i][2], acc[i][3]);
    }
}

// ---------------------------------------------------------------- gather + epilogue
// out[c] = tanh( dinv[c] * sum_j sdnv[j]*xw[srow[j]] + dinv[c]^2*xw[c] + b )
// 32 lanes per node, float4 per lane (128 dims). No atomics, write-once.
__global__ __launch_bounds__(256) void k_gather_act(const float* __restrict__ xw,
                                                    const int* __restrict__ srow,
                                                    const float* __restrict__ sdnv,
                                                    const int* __restrict__ cursor,
                                                    const float* __restrict__ dinv,
                                                    const float* __restrict__ b,
                                                    float* __restrict__ out) {
    const int tid = threadIdx.x;
    const int node = blockIdx.x * 8 + (tid >> 5);
    if (node >= N_NODES) return;
    const int ch = (tid & 31) * 4;

    const int start = (node == 0) ? 0 : cursor[node - 1];
    const int end = cursor[node];

    float4 acc = make_float4(0.f, 0.f, 0.f, 0.f);
    for (int j = start; j < end; ++j) {
        const int r = srow[j];          // broadcast across the 32-lane group
        const float w = sdnv[j];
        const float4 v = *reinterpret_cast<const float4*>(xw + (size_t)r * HID + ch);
        acc.x += w * v.x;
        acc.y += w * v.y;
        acc.z += w * v.z;
        acc.w += w * v.w;
    }

    const float dc = dinv[node];
    const float s = dc * dc;
    const float4 xv = *reinterpret_cast<const float4*>(xw + (size_t)node * HID + ch);
    const float4 bv = *reinterpret_cast<const float4*>(b + ch);
    float4 o;
    o.x = tanhf(dc * acc.x + s * xv.x + bv.x);
    o.y = tanhf(dc * acc.y + s * xv.y + bv.y);
    o.z = tanhf(dc * acc.z + s * xv.z + bv.z);
    o.w = tanhf(dc * acc.w + s * xv.w + bv.w);
    *reinterpret_cast<float4*>(out + (size_t)node * HID + ch) = o;
}

// ---------------------------------------------------------------- launch
extern "C" void kernel_launch(void* const* d_in, const int* in_sizes, int n_in,
                              void* d_out, int out_size, void* d_ws, size_t ws_size,
                              hipStream_t stream) {
    const float* x  = (const float*)d_in[0];
    const int*   ei = (const int*)d_in[1];
    const int*   row = ei;                       // edge_index[0]
    const int*   col = ei + N_EDGES;             // edge_index[1]
    const float* W1 = (const float*)d_in[2];
    const float* b1 = (const float*)d_in[3];
    const float* W2 = (const float*)d_in[4];
    const float* b2 = (const float*)d_in[5];
    float* out = (float*)d_out;

    // workspace layout (~65 MB): bufA | dinv | deg | cursor | bsum | srow | sdnv
    float* bufA   = (float*)d_ws;                                  // [N,128] xw
    float* dinv   = bufA + (size_t)N_NODES * HID;
    int*   deg    = (int*)(dinv + N_NODES);
    int*   cursor = deg + N_NODES;
    int*   bsum   = cursor + N_NODES;
    int*   srow   = bsum + 512;
    float* sdnv   = (float*)(srow + N_EDGES);

    // ---- CSR build (shared by both layers)
    hipMemsetAsync(deg, 0, N_NODES * sizeof(int), stream);
    k_count<<<(N_EDGES + 255) / 256, 256, 0, stream>>>(col, deg);
    k_dinv<<<(N_NODES + 255) / 256, 256, 0, stream>>>(deg, dinv);
    k_scan1<<<SCAN_BLOCKS, 256, 0, stream>>>(deg, cursor, bsum);
    k_scan2<<<1, 512, 0, stream>>>(bsum, SCAN_BLOCKS);
    k_scan3<<<SCAN_BLOCKS, 256, 0, stream>>>(cursor, bsum);
    k_place<<<(N_EDGES + 255) / 256, 256, 0, stream>>>(row, col, dinv, cursor, srow, sdnv);

    // ---- layer 1: h1 = tanh(agg(x@W1) + self + b1) -> d_out (temp storage)
    k_gemm<256><<<N_NODES / 32, 256, 0, stream>>>(x, W1, bufA);
    k_gather_act<<<N_NODES / 8, 256, 0, stream>>>(bufA, srow, sdnv, cursor, dinv, b1, out);

    // ---- layer 2: out = tanh(agg(h1@W2) + self + b2), h1 read from d_out
    k_gemm<128><<<N_NODES / 32, 256, 0, stream>>>(out, W2, bufA);
    k_gather_act<<<N_NODES / 8, 256, 0, stream>>>(bufA, srow, sdnv, cursor, dinv, b2, out);
}

// Round 8
// 651.780 us; speedup vs baseline: 8.9326x; 1.1861x over previous
//
#include <hip/hip_runtime.h>
#include <cstdint>
#include <cstddef>

#define N_NODES 100000
#define N_EDGES 1600000
#define HID 128
#define SCAN_BLOCKS ((N_NODES + 255) / 256)   // 391

using frag_ab = __attribute__((ext_vector_type(8))) short;  // 8 bf16 (4 VGPRs)
using f32x4   = __attribute__((ext_vector_type(4))) float;  // MFMA accumulator

__device__ __forceinline__ short f2bf(float f) {            // RNE f32->bf16
    uint32_t u = __builtin_bit_cast(uint32_t, f);
    u += 0x7fffu + ((u >> 16) & 1u);
    return (short)(u >> 16);
}

// ---------------------------------------------------------------- deg histogram
__global__ __launch_bounds__(256) void k_count(const int* __restrict__ col,
                                               int* __restrict__ deg) {
    int e = blockIdx.x * 256 + threadIdx.x;
    if (e < N_EDGES) atomicAdd(&deg[col[e]], 1);
}

__global__ __launch_bounds__(256) void k_dinv(const int* __restrict__ deg,
                                              float* __restrict__ dinv) {
    int i = blockIdx.x * 256 + threadIdx.x;
    if (i < N_NODES) dinv[i] = rsqrtf((float)deg[i] + 1.0f);  // +1 self-loop
}

// ---------------------------------------------------------------- exclusive scan
__global__ __launch_bounds__(256) void k_scan1(const int* __restrict__ deg,
                                               int* __restrict__ cursor,
                                               int* __restrict__ bsum) {
    __shared__ int s[256];
    const int t = threadIdx.x;
    const int i = blockIdx.x * 256 + t;
    int v = (i < N_NODES) ? deg[i] : 0;
    s[t] = v;
    __syncthreads();
#pragma unroll
    for (int d = 1; d < 256; d <<= 1) {
        int a = (t >= d) ? s[t - d] : 0;
        __syncthreads();
        s[t] += a;
        __syncthreads();
    }
    if (i < N_NODES) cursor[i] = s[t] - v;
    if (t == 255) bsum[blockIdx.x] = s[t];
}

__global__ __launch_bounds__(512) void k_scan2(int* __restrict__ bsum, int n) {
    __shared__ int s[512];
    const int t = threadIdx.x;
    int v = (t < n) ? bsum[t] : 0;
    s[t] = v;
    __syncthreads();
#pragma unroll
    for (int d = 1; d < 512; d <<= 1) {
        int a = (t >= d) ? s[t - d] : 0;
        __syncthreads();
        s[t] += a;
        __syncthreads();
    }
    if (t < n) bsum[t] = s[t] - v;
}

__global__ __launch_bounds__(256) void k_scan3(int* __restrict__ cursor,
                                               const int* __restrict__ bsum) {
    const int i = blockIdx.x * 256 + threadIdx.x;
    if (i < N_NODES) cursor[i] += bsum[blockIdx.x];
}

// ---------------------------------------------------------------- CSR placement
__global__ __launch_bounds__(256) void k_place(const int* __restrict__ row,
                                               const int* __restrict__ col,
                                               const float* __restrict__ dinv,
                                               int* __restrict__ cursor,
                                               int* __restrict__ srow,
                                               float* __restrict__ sdnv) {
    const int e = blockIdx.x * 256 + threadIdx.x;
    if (e >= N_EDGES) return;
    const int r = row[e];
    const int c = col[e];
    const int p = atomicAdd(&cursor[c], 1);
    srow[p] = r;
    sdnv[p] = dinv[r];
}

// ---------------------------------------------------------------- W -> Wt (bf16, transposed)
// Wt[n][k] = bf16(W[k][n]);  W is [K][128] row-major.
template <int K>
__global__ __launch_bounds__(256) void k_wt(const float* __restrict__ W,
                                            short* __restrict__ Wt) {
    const int idx = blockIdx.x * 256 + threadIdx.x;
    if (idx >= K * HID) return;
    const int k = idx >> 7;          // / 128
    const int n = idx & 127;
    Wt[n * K + k] = f2bf(W[idx]);
}

// ---------------------------------------------------------------- bf16 MFMA GEMM
// C[M,128] = A[M,K](f32, converted in-register) @ W[K,128] (as Wt[n][k] bf16).
// Block: 256 threads = 4 waves; BM=128. Wave w owns rows {w*16..+16} and
// {64+w*16..+16} (2 row-frags), all 8 col-frags. No LDS; Wt is L2-resident.
// mfma_f32_16x16x32_bf16 layouts (learn_hip m89): A: row=l&15, k=(l>>4)*8+j;
// B: k=(l>>4)*8+j, col=l&15; C/D: col=l&15, row=(l>>4)*4+reg.
template <int K>
__global__ __launch_bounds__(256) void k_mfma(const float* __restrict__ A,
                                              const short* __restrict__ Wt,
                                              float* __restrict__ C) {
    const int tid  = threadIdx.x;
    const int w    = tid >> 6;          // wave 0..3
    const int lane = tid & 63;
    const int l15  = lane & 15;
    const int kg   = lane >> 4;         // k-group 0..3
    const int m0   = blockIdx.x * 128;

    f32x4 acc[2][8];
#pragma unroll
    for (int rb = 0; rb < 2; ++rb)
#pragma unroll
        for (int c = 0; c < 8; ++c)
            acc[rb][c] = (f32x4){0.f, 0.f, 0.f, 0.f};

    for (int k0 = 0; k0 < K; k0 += 32) {
        // A fragments: 8 contiguous f32 -> bf16x8
        frag_ab afr[2];
#pragma unroll
        for (int rb = 0; rb < 2; ++rb) {
            int ar = m0 + w * 16 + rb * 64 + l15;
            if (ar >= N_NODES) ar = N_NODES - 1;     // tail clamp (store predicated)
            const float4* ap =
                reinterpret_cast<const float4*>(A + (size_t)ar * K + k0 + kg * 8);
            const float4 v0 = ap[0];
            const float4 v1 = ap[1];
            afr[rb][0] = f2bf(v0.x); afr[rb][1] = f2bf(v0.y);
            afr[rb][2] = f2bf(v0.z); afr[rb][3] = f2bf(v0.w);
            afr[rb][4] = f2bf(v1.x); afr[rb][5] = f2bf(v1.y);
            afr[rb][6] = f2bf(v1.z); afr[rb][7] = f2bf(v1.w);
        }
#pragma unroll
        for (int c = 0; c < 8; ++c) {
            const frag_ab bfr = *reinterpret_cast<const frag_ab*>(
                Wt + (size_t)(c * 16 + l15) * K + k0 + kg * 8);
            acc[0][c] = __builtin_amdgcn_mfma_f32_16x16x32_bf16(afr[0], bfr, acc[0][c], 0, 0, 0);
            acc[1][c] = __builtin_amdgcn_mfma_f32_16x16x32_bf16(afr[1], bfr, acc[1][c], 0, 0, 0);
        }
    }

    // store: row = base + (lane>>4)*4 + i, col = c*16 + (lane&15)
#pragma unroll
    for (int rb = 0; rb < 2; ++rb) {
        const int rbase = m0 + w * 16 + rb * 64 + kg * 4;
#pragma unroll
        for (int c = 0; c < 8; ++c) {
#pragma unroll
            for (int i = 0; i < 4; ++i) {
                const int rr = rbase + i;
                if (rr < N_NODES) C[(size_t)rr * HID + c * 16 + l15] = acc[rb][c][i];
            }
        }
    }
}

// ---------------------------------------------------------------- gather + epilogue
// out[c] = tanh( dinv[c] * sum_j sdnv[j]*xw[srow[j]] + dinv[c]^2*xw[c] + b )
__global__ __launch_bounds__(256) void k_gather_act(const float* __restrict__ xw,
                                                    const int* __restrict__ srow,
                                                    const float* __restrict__ sdnv,
                                                    const int* __restrict__ cursor,
                                                    const float* __restrict__ dinv,
                                                    const float* __restrict__ b,
                                                    float* __restrict__ out) {
    const int tid = threadIdx.x;
    const int node = blockIdx.x * 8 + (tid >> 5);
    if (node >= N_NODES) return;
    const int ch = (tid & 31) * 4;

    const int start = (node == 0) ? 0 : cursor[node - 1];
    const int end = cursor[node];

    float4 acc = make_float4(0.f, 0.f, 0.f, 0.f);
    for (int j = start; j < end; ++j) {
        const int r = srow[j];
        const float w = sdnv[j];
        const float4 v = *reinterpret_cast<const float4*>(xw + (size_t)r * HID + ch);
        acc.x += w * v.x;
        acc.y += w * v.y;
        acc.z += w * v.z;
        acc.w += w * v.w;
    }

    const float dc = dinv[node];
    const float s = dc * dc;
    const float4 xv = *reinterpret_cast<const float4*>(xw + (size_t)node * HID + ch);
    const float4 bv = *reinterpret_cast<const float4*>(b + ch);
    float4 o;
    o.x = tanhf(dc * acc.x + s * xv.x + bv.x);
    o.y = tanhf(dc * acc.y + s * xv.y + bv.y);
    o.z = tanhf(dc * acc.z + s * xv.z + bv.z);
    o.w = tanhf(dc * acc.w + s * xv.w + bv.w);
    *reinterpret_cast<float4*>(out + (size_t)node * HID + ch) = o;
}

// ---------------------------------------------------------------- launch
extern "C" void kernel_launch(void* const* d_in, const int* in_sizes, int n_in,
                              void* d_out, int out_size, void* d_ws, size_t ws_size,
                              hipStream_t stream) {
    const float* x  = (const float*)d_in[0];
    const int*   ei = (const int*)d_in[1];
    const int*   row = ei;                       // edge_index[0]
    const int*   col = ei + N_EDGES;             // edge_index[1]
    const float* W1 = (const float*)d_in[2];
    const float* b1 = (const float*)d_in[3];
    const float* W2 = (const float*)d_in[4];
    const float* b2 = (const float*)d_in[5];
    float* out = (float*)d_out;

    // workspace (~65.4 MB): bufA | dinv | deg | cursor | bsum | srow | sdnv | wt1 | wt2
    float* bufA   = (float*)d_ws;                                  // [N,128] xw
    float* dinv   = bufA + (size_t)N_NODES * HID;
    int*   deg    = (int*)(dinv + N_NODES);
    int*   cursor = deg + N_NODES;
    int*   bsum   = cursor + N_NODES;
    int*   srow   = bsum + 512;
    float* sdnv   = (float*)(srow + N_EDGES);
    short* wt1    = (short*)(sdnv + N_EDGES);                      // [128][256] bf16
    short* wt2    = wt1 + 128 * 256;                               // [128][128] bf16

    // ---- weight transpose+convert (tiny)
    k_wt<256><<<(256 * HID + 255) / 256, 256, 0, stream>>>(W1, wt1);
    k_wt<128><<<(128 * HID + 255) / 256, 256, 0, stream>>>(W2, wt2);

    // ---- CSR build (shared by both layers)
    hipMemsetAsync(deg, 0, N_NODES * sizeof(int), stream);
    k_count<<<(N_EDGES + 255) / 256, 256, 0, stream>>>(col, deg);
    k_dinv<<<(N_NODES + 255) / 256, 256, 0, stream>>>(deg, dinv);
    k_scan1<<<SCAN_BLOCKS, 256, 0, stream>>>(deg, cursor, bsum);
    k_scan2<<<1, 512, 0, stream>>>(bsum, SCAN_BLOCKS);
    k_scan3<<<SCAN_BLOCKS, 256, 0, stream>>>(cursor, bsum);
    k_place<<<(N_EDGES + 255) / 256, 256, 0, stream>>>(row, col, dinv, cursor, srow, sdnv);

    // ---- layer 1: h1 = tanh(agg(x@W1) + self + b1) -> d_out (temp storage)
    k_mfma<256><<<(N_NODES + 127) / 128, 256, 0, stream>>>(x, wt1, bufA);
    k_gather_act<<<N_NODES / 8, 256, 0, stream>>>(bufA, srow, sdnv, cursor, dinv, b1, out);

    // ---- layer 2: out = tanh(agg(h1@W2) + self + b2), h1 read from d_out
    k_mfma<128><<<(N_NODES + 127) / 128, 256, 0, stream>>>(out, wt2, bufA);
    k_gather_act<<<N_NODES / 8, 256, 0, stream>>>(bufA, srow, sdnv, cursor, dinv, b2, out);
}

// Round 11
// 558.311 us; speedup vs baseline: 10.4280x; 1.1674x over previous
//
#include <hip/hip_runtime.h>
#include <cstdint>
#include <cstddef>

#define N_NODES 100000
#define N_EDGES 1600000
#define HID 128
#define SCAN_BLOCKS ((N_NODES + 255) / 256)   // 391

using frag_ab = __attribute__((ext_vector_type(8))) short;  // 8 bf16 (4 VGPRs)
using f32x4   = __attribute__((ext_vector_type(4))) float;  // MFMA accumulator

__device__ __forceinline__ unsigned short f2bf(float f) {   // RNE f32->bf16
    uint32_t u = __builtin_bit_cast(uint32_t, f);
    u += 0x7fffu + ((u >> 16) & 1u);
    return (unsigned short)(u >> 16);
}
__device__ __forceinline__ float bf2f(unsigned short u) {
    uint32_t v = (uint32_t)u << 16;
    return __builtin_bit_cast(float, v);
}

// ---------------------------------------------------------------- deg histogram
__global__ __launch_bounds__(256) void k_count(const int* __restrict__ col,
                                               int* __restrict__ deg) {
    int e = blockIdx.x * 256 + threadIdx.x;
    if (e < N_EDGES) atomicAdd(&deg[col[e]], 1);
}

__global__ __launch_bounds__(256) void k_dinv(const int* __restrict__ deg,
                                              float* __restrict__ dinv) {
    int i = blockIdx.x * 256 + threadIdx.x;
    if (i < N_NODES) dinv[i] = rsqrtf((float)deg[i] + 1.0f);  // +1 self-loop
}

// ---------------------------------------------------------------- exclusive scan
__global__ __launch_bounds__(256) void k_scan1(const int* __restrict__ deg,
                                               int* __restrict__ cursor,
                                               int* __restrict__ bsum) {
    __shared__ int s[256];
    const int t = threadIdx.x;
    const int i = blockIdx.x * 256 + t;
    int v = (i < N_NODES) ? deg[i] : 0;
    s[t] = v;
    __syncthreads();
#pragma unroll
    for (int d = 1; d < 256; d <<= 1) {
        int a = (t >= d) ? s[t - d] : 0;
        __syncthreads();
        s[t] += a;
        __syncthreads();
    }
    if (i < N_NODES) cursor[i] = s[t] - v;
    if (t == 255) bsum[blockIdx.x] = s[t];
}

__global__ __launch_bounds__(512) void k_scan2(int* __restrict__ bsum, int n) {
    __shared__ int s[512];
    const int t = threadIdx.x;
    int v = (t < n) ? bsum[t] : 0;
    s[t] = v;
    __syncthreads();
#pragma unroll
    for (int d = 1; d < 512; d <<= 1) {
        int a = (t >= d) ? s[t - d] : 0;
        __syncthreads();
        s[t] += a;
        __syncthreads();
    }
    if (t < n) bsum[t] = s[t] - v;
}

__global__ __launch_bounds__(256) void k_scan3(int* __restrict__ cursor,
                                               const int* __restrict__ bsum) {
    const int i = blockIdx.x * 256 + threadIdx.x;
    if (i < N_NODES) cursor[i] += bsum[blockIdx.x];
}

// ---------------------------------------------------------------- CSR placement
__global__ __launch_bounds__(256) void k_place(const int* __restrict__ row,
                                               const int* __restrict__ col,
                                               const float* __restrict__ dinv,
                                               int* __restrict__ cursor,
                                               int* __restrict__ srow,
                                               float* __restrict__ sdnv) {
    const int e = blockIdx.x * 256 + threadIdx.x;
    if (e >= N_EDGES) return;
    const int r = row[e];
    const int c = col[e];
    const int p = atomicAdd(&cursor[c], 1);
    srow[p] = r;
    sdnv[p] = dinv[r];
}

// ---------------------------------------------------------------- W -> Wt (bf16, transposed)
template <int K>
__global__ __launch_bounds__(256) void k_wt(const float* __restrict__ W,
                                            short* __restrict__ Wt) {
    const int idx = blockIdx.x * 256 + threadIdx.x;
    if (idx >= K * HID) return;
    const int k = idx >> 7;          // / 128
    const int n = idx & 127;
    Wt[n * K + k] = (short)f2bf(W[idx]);
}

// ---------------------------------------------------------------- bf16 MFMA GEMM (A = f32)
// C[M,128](bf16) = A[M,K](f32, converted in-register) @ Wt[n][k](bf16).
// mfma_f32_16x16x32_bf16 layouts (learn_hip m89): A: row=l&15, k=(l>>4)*8+j;
// B: k=(l>>4)*8+j, col=l&15; C/D: col=l&15, row=(l>>4)*4+reg.
template <int K>
__global__ __launch_bounds__(256) void k_mfma_f32A(const float* __restrict__ A,
                                                   const short* __restrict__ Wt,
                                                   unsigned short* __restrict__ C) {
    const int tid  = threadIdx.x;
    const int w    = tid >> 6;
    const int lane = tid & 63;
    const int l15  = lane & 15;
    const int kg   = lane >> 4;
    const int m0   = blockIdx.x * 128;

    f32x4 acc[2][8];
#pragma unroll
    for (int rb = 0; rb < 2; ++rb)
#pragma unroll
        for (int c = 0; c < 8; ++c)
            acc[rb][c] = (f32x4){0.f, 0.f, 0.f, 0.f};

    for (int k0 = 0; k0 < K; k0 += 32) {
        frag_ab afr[2];
#pragma unroll
        for (int rb = 0; rb < 2; ++rb) {
            int ar = m0 + w * 16 + rb * 64 + l15;
            if (ar >= N_NODES) ar = N_NODES - 1;     // tail clamp (store predicated)
            const float4* ap =
                reinterpret_cast<const float4*>(A + (size_t)ar * K + k0 + kg * 8);
            const float4 v0 = ap[0];
            const float4 v1 = ap[1];
            afr[rb][0] = (short)f2bf(v0.x); afr[rb][1] = (short)f2bf(v0.y);
            afr[rb][2] = (short)f2bf(v0.z); afr[rb][3] = (short)f2bf(v0.w);
            afr[rb][4] = (short)f2bf(v1.x); afr[rb][5] = (short)f2bf(v1.y);
            afr[rb][6] = (short)f2bf(v1.z); afr[rb][7] = (short)f2bf(v1.w);
        }
#pragma unroll
        for (int c = 0; c < 8; ++c) {
            const frag_ab bfr = *reinterpret_cast<const frag_ab*>(
                Wt + (size_t)(c * 16 + l15) * K + k0 + kg * 8);
            acc[0][c] = __builtin_amdgcn_mfma_f32_16x16x32_bf16(afr[0], bfr, acc[0][c], 0, 0, 0);
            acc[1][c] = __builtin_amdgcn_mfma_f32_16x16x32_bf16(afr[1], bfr, acc[1][c], 0, 0, 0);
        }
    }
#pragma unroll
    for (int rb = 0; rb < 2; ++rb) {
        const int rbase = m0 + w * 16 + rb * 64 + kg * 4;
#pragma unroll
        for (int c = 0; c < 8; ++c)
#pragma unroll
            for (int i = 0; i < 4; ++i) {
                const int rr = rbase + i;
                if (rr < N_NODES) C[(size_t)rr * HID + c * 16 + l15] = f2bf(acc[rb][c][i]);
            }
    }
}

// ---------------------------------------------------------------- bf16 MFMA GEMM (A = bf16)
// Same, but A rows are already bf16 — fragment is a direct 16 B load.
template <int K>
__global__ __launch_bounds__(256) void k_mfma_bf16A(const unsigned short* __restrict__ A,
                                                    const short* __restrict__ Wt,
                                                    unsigned short* __restrict__ C) {
    const int tid  = threadIdx.x;
    const int w    = tid >> 6;
    const int lane = tid & 63;
    const int l15  = lane & 15;
    const int kg   = lane >> 4;
    const int m0   = blockIdx.x * 128;

    f32x4 acc[2][8];
#pragma unroll
    for (int rb = 0; rb < 2; ++rb)
#pragma unroll
        for (int c = 0; c < 8; ++c)
            acc[rb][c] = (f32x4){0.f, 0.f, 0.f, 0.f};

    for (int k0 = 0; k0 < K; k0 += 32) {
        frag_ab afr[2];
#pragma unroll
        for (int rb = 0; rb < 2; ++rb) {
            int ar = m0 + w * 16 + rb * 64 + l15;
            if (ar >= N_NODES) ar = N_NODES - 1;
            afr[rb] = *reinterpret_cast<const frag_ab*>(A + (size_t)ar * K + k0 + kg * 8);
        }
#pragma unroll
        for (int c = 0; c < 8; ++c) {
            const frag_ab bfr = *reinterpret_cast<const frag_ab*>(
                Wt + (size_t)(c * 16 + l15) * K + k0 + kg * 8);
            acc[0][c] = __builtin_amdgcn_mfma_f32_16x16x32_bf16(afr[0], bfr, acc[0][c], 0, 0, 0);
            acc[1][c] = __builtin_amdgcn_mfma_f32_16x16x32_bf16(afr[1], bfr, acc[1][c], 0, 0, 0);
        }
    }
#pragma unroll
    for (int rb = 0; rb < 2; ++rb) {
        const int rbase = m0 + w * 16 + rb * 64 + kg * 4;
#pragma unroll
        for (int c = 0; c < 8; ++c)
#pragma unroll
            for (int i = 0; i < 4; ++i) {
                const int rr = rbase + i;
                if (rr < N_NODES) C[(size_t)rr * HID + c * 16 + l15] = f2bf(acc[rb][c][i]);
            }
    }
}

// ---------------------------------------------------------------- gather + epilogue
// out[c] = tanh( dinv[c] * sum_j sdnv[j]*xw[srow[j]] + dinv[c]^2*xw[c] + b )
// xw rows are bf16 (256 B/row); f32 accumulate. OUT_BF16 selects h1(bf16) vs final(f32).
template <bool OUT_BF16>
__global__ __launch_bounds__(256) void k_gather_act(const unsigned short* __restrict__ xw,
                                                    const int* __restrict__ srow,
                                                    const float* __restrict__ sdnv,
                                                    const int* __restrict__ cursor,
                                                    const float* __restrict__ dinv,
                                                    const float* __restrict__ b,
                                                    void* __restrict__ outv) {
    const int tid = threadIdx.x;
    const int node = blockIdx.x * 8 + (tid >> 5);
    if (node >= N_NODES) return;
    const int ch = (tid & 31) * 4;               // 4 bf16 per lane (8 B)

    const int start = (node == 0) ? 0 : cursor[node - 1];
    const int end = cursor[node];

    float4 acc = make_float4(0.f, 0.f, 0.f, 0.f);
#pragma unroll 2
    for (int j = start; j < end; ++j) {
        const int r = srow[j];
        const float w = sdnv[j];
        const ushort4 v = *reinterpret_cast<const ushort4*>(xw + (size_t)r * HID + ch);
        acc.x += w * bf2f(v.x);
        acc.y += w * bf2f(v.y);
        acc.z += w * bf2f(v.z);
        acc.w += w * bf2f(v.w);
    }

    const float dc = dinv[node];
    const float s = dc * dc;
    const ushort4 xv = *reinterpret_cast<const ushort4*>(xw + (size_t)node * HID + ch);
    const float4 bv = *reinterpret_cast<const float4*>(b + ch);
    float o0 = tanhf(dc * acc.x + s * bf2f(xv.x) + bv.x);
    float o1 = tanhf(dc * acc.y + s * bf2f(xv.y) + bv.y);
    float o2 = tanhf(dc * acc.z + s * bf2f(xv.z) + bv.z);
    float o3 = tanhf(dc * acc.w + s * bf2f(xv.w) + bv.w);

    if (OUT_BF16) {
        ushort4 o = {f2bf(o0), f2bf(o1), f2bf(o2), f2bf(o3)};
        *reinterpret_cast<ushort4*>((unsigned short*)outv + (size_t)node * HID + ch) = o;
    } else {
        *reinterpret_cast<float4*>((float*)outv + (size_t)node * HID + ch) =
            make_float4(o0, o1, o2, o3);
    }
}

// ---------------------------------------------------------------- launch
extern "C" void kernel_launch(void* const* d_in, const int* in_sizes, int n_in,
                              void* d_out, int out_size, void* d_ws, size_t ws_size,
                              hipStream_t stream) {
    const float* x  = (const float*)d_in[0];
    const int*   ei = (const int*)d_in[1];
    const int*   row = ei;                       // edge_index[0]
    const int*   col = ei + N_EDGES;             // edge_index[1]
    const float* W1 = (const float*)d_in[2];
    const float* b1 = (const float*)d_in[3];
    const float* W2 = (const float*)d_in[4];
    const float* b2 = (const float*)d_in[5];
    float* out = (float*)d_out;

    // workspace (~65 MB): xwb | h1b | dinv | deg | cursor | bsum | srow | sdnv | wt1 | wt2
    unsigned short* xwb = (unsigned short*)d_ws;                   // [N,128] bf16
    unsigned short* h1b = xwb + (size_t)N_NODES * HID;             // [N,128] bf16
    float* dinv   = (float*)(h1b + (size_t)N_NODES * HID);
    int*   deg    = (int*)(dinv + N_NODES);
    int*   cursor = deg + N_NODES;
    int*   bsum   = cursor + N_NODES;
    int*   srow   = bsum + 512;
    float* sdnv   = (float*)(srow + N_EDGES);
    short* wt1    = (short*)(sdnv + N_EDGES);                      // [128][256] bf16
    short* wt2    = wt1 + 128 * 256;                               // [128][128] bf16

    // ---- weight transpose+convert (tiny)
    k_wt<256><<<(256 * HID + 255) / 256, 256, 0, stream>>>(W1, wt1);
    k_wt<128><<<(128 * HID + 255) / 256, 256, 0, stream>>>(W2, wt2);

    // ---- CSR build (shared by both layers)
    hipMemsetAsync(deg, 0, N_NODES * sizeof(int), stream);
    k_count<<<(N_EDGES + 255) / 256, 256, 0, stream>>>(col, deg);
    k_dinv<<<(N_NODES + 255) / 256, 256, 0, stream>>>(deg, dinv);
    k_scan1<<<SCAN_BLOCKS, 256, 0, stream>>>(deg, cursor, bsum);
    k_scan2<<<1, 512, 0, stream>>>(bsum, SCAN_BLOCKS);
    k_scan3<<<SCAN_BLOCKS, 256, 0, stream>>>(cursor, bsum);
    k_place<<<(N_EDGES + 255) / 256, 256, 0, stream>>>(row, col, dinv, cursor, srow, sdnv);

    // ---- layer 1: h1b = bf16(tanh(agg(x@W1) + self + b1))
    k_mfma_f32A<256><<<(N_NODES + 127) / 128, 256, 0, stream>>>(x, wt1, xwb);
    k_gather_act<true><<<N_NODES / 8, 256, 0, stream>>>(xwb, srow, sdnv, cursor, dinv, b1, h1b);

    // ---- layer 2: out = tanh(agg(h1b@W2) + self + b2)
    k_mfma_bf16A<128><<<(N_NODES + 127) / 128, 256, 0, stream>>>(h1b, wt2, xwb);
    k_gather_act<false><<<N_NODES / 8, 256, 0, stream>>>(xwb, srow, sdnv, cursor, dinv, b2, out);
}